// Round 12
// baseline (331.069 us; speedup 1.0000x reference)
//
#include <hip/hip_runtime.h>
#include <math.h>

#define DM 256
#define NROWS 8192
#define NCOLS 8192
#define LOG2E 1.44269504f
#define LN2F 0.6931471805599453f

typedef __attribute__((ext_vector_type(8)))  __bf16 bf16x8;
typedef __attribute__((ext_vector_type(4)))  __bf16 bf16x4;
typedef __attribute__((ext_vector_type(16))) float  f32x16;

#if __has_builtin(__builtin_amdgcn_exp2f)
#define EXP2F(x) __builtin_amdgcn_exp2f(x)
#else
#define EXP2F(x) exp2f(x)
#endif

__device__ __forceinline__ f32x16 fzero16() {
  f32x16 z;
#pragma unroll
  for (int i = 0; i < 16; ++i) z[i] = 0.f;
  return z;
}

__device__ __forceinline__ void load_lds16(const void* g, void* l) {
  __builtin_amdgcn_global_load_lds(
      (const __attribute__((address_space(1))) unsigned int*)g,
      (__attribute__((address_space(3))) unsigned int*)l, 16, 0, 0);
}

__device__ __forceinline__ bf16x8 cvt8(float4 a, float4 b) {
  bf16x8 v;
  v[0] = (__bf16)a.x; v[1] = (__bf16)a.y; v[2] = (__bf16)a.z; v[3] = (__bf16)a.w;
  v[4] = (__bf16)b.x; v[5] = (__bf16)b.y; v[6] = (__bf16)b.z; v[7] = (__bf16)b.w;
  return v;
}

__device__ __forceinline__ unsigned cvtpk_bf16(float lo, float hi) {
  unsigned r;
  asm("v_cvt_pk_bf16_f32 %0, %1, %2" : "=v"(r) : "v"(lo), "v"(hi));
  return r;
}
__device__ __forceinline__ void swap32(unsigned& a, unsigned& b) {
  asm("v_permlane32_swap_b32 %0, %1" : "+v"(a), "+v"(b));
}

// ---- weight convert+transpose: wt[mat][n][k] (bf16) = W[mat][k][n] ----
__global__ __launch_bounds__(256) void convert_w_kernel(
    const float* __restrict__ W0, const float* __restrict__ W1,
    const float* __restrict__ W2, const float* __restrict__ W3,
    __bf16* __restrict__ wt) {
  __shared__ float Ls[64][65];
  const int t = threadIdx.x;
  const int mat = blockIdx.x >> 4;
  const int k0 = ((blockIdx.x >> 2) & 3) * 64;
  const int n0 = (blockIdx.x & 3) * 64;
  const float* W = mat == 0 ? W0 : mat == 1 ? W1 : mat == 2 ? W2 : W3;
#pragma unroll
  for (int i = 0; i < 4; ++i) {
    int idx = t + i * 256;
    int row = idx >> 4, c4 = (idx & 15) * 4;
    float4 v = *(const float4*)&W[(size_t)(k0 + row) * DM + n0 + c4];
    Ls[row][c4] = v.x; Ls[row][c4 + 1] = v.y;
    Ls[row][c4 + 2] = v.z; Ls[row][c4 + 3] = v.w;
  }
  __syncthreads();
#pragma unroll
  for (int i = 0; i < 2; ++i) {
    int c = t + i * 256;
    int n = c >> 3, kc = (c & 7) * 8;
    bf16x8 v;
#pragma unroll
    for (int j = 0; j < 8; ++j) v[j] = (__bf16)Ls[kc + j][n];
    *(bf16x8*)&wt[(size_t)mat * 65536 + (size_t)(n0 + n) * DM + k0 + kc] = v;
  }
}

// ---- label histogram ----
__global__ __launch_bounds__(1024) void hist_kernel(
    const int* __restrict__ lab2, int* __restrict__ counts) {
  __shared__ int h[16];
  const int t = threadIdx.x;
  if (t < 16) h[t] = 0;
  __syncthreads();
  int4 a = *(const int4*)&lab2[t * 8];
  int4 b = *(const int4*)&lab2[t * 8 + 4];
  atomicAdd(&h[a.x & 15], 1); atomicAdd(&h[a.y & 15], 1);
  atomicAdd(&h[a.z & 15], 1); atomicAdd(&h[a.w & 15], 1);
  atomicAdd(&h[b.x & 15], 1); atomicAdd(&h[b.y & 15], 1);
  atomicAdd(&h[b.z & 15], 1); atomicAdd(&h[b.w & 15], 1);
  __syncthreads();
  if (t < 16) counts[t] = h[t];
}

// ---- fused 3-projection MFMA GEMM (grid.z = mat) ----
__global__ __launch_bounds__(256) void proj3_kernel(
    const float* __restrict__ x1, const float* __restrict__ x2,
    const __bf16* __restrict__ wt, const float* __restrict__ bxq,
    const float* __restrict__ bxk, const float* __restrict__ bxv,
    __bf16* __restrict__ xqb, __bf16* __restrict__ xkb,
    __bf16* __restrict__ xvT) {
  __shared__ __bf16 W_s[64 * 256];
  const int t = threadIdx.x;
  const int w = t >> 6, l = t & 63, g = l >> 5, l31 = l & 31;
  const int mb = blockIdx.x, nt = blockIdx.y, mat = blockIdx.z;
  const int n0 = nt * 64;
  const float* A = (mat == 0) ? x1 : x2;
  const __bf16* wmat = wt + (size_t)mat * 65536;
  const float* bias = (mat == 0) ? bxq : (mat == 1) ? bxk : bxv;
  const float oscale = (mat == 0) ? (0.0625f * LOG2E) : 1.0f;
#pragma unroll
  for (int o = 0; o < 8; ++o) {
    int cbase = w * 64 + o * 256;
    int chunk = cbase + l;
    int n = chunk >> 5, kb = (chunk & 31) * 16;
    load_lds16((const char*)wmat + (size_t)(n0 + n) * 512 + (kb ^ ((n & 7) << 4)),
               (char*)W_s + (size_t)cbase * 16);
  }
  const int arow = mb * 128 + w * 32 + l31;
  bf16x8 af[16];
#pragma unroll
  for (int ks = 0; ks < 16; ++ks) {
    float4 u0 = *(const float4*)&A[(size_t)arow * DM + ks * 16 + g * 8];
    float4 u1 = *(const float4*)&A[(size_t)arow * DM + ks * 16 + g * 8 + 4];
    af[ks] = cvt8(u0, u1);
  }
  __syncthreads();
  f32x16 acc2[2];
  acc2[0] = fzero16(); acc2[1] = fzero16();
#pragma unroll
  for (int ks = 0; ks < 16; ++ks)
#pragma unroll
    for (int tt = 0; tt < 2; ++tt) {
      int n = tt * 32 + l31;
      bf16x8 b = *(const bf16x8*)&W_s[n * DM + ((ks * 16 + g * 8) ^ ((n & 7) << 3))];
      acc2[tt] = __builtin_amdgcn_mfma_f32_32x32x16_bf16(af[ks], b, acc2[tt], 0, 0, 0);
    }
  const int mrowbase = mb * 128 + w * 32;
#pragma unroll
  for (int tt = 0; tt < 2; ++tt) {
    const int col = n0 + tt * 32 + l31;
    const float bv = bias[col];
    if (mat == 2) {
#pragma unroll
      for (int rq = 0; rq < 4; ++rq) {
        int m = mrowbase + 8 * rq + 4 * g;
        bf16x4 v;
#pragma unroll
        for (int j = 0; j < 4; ++j) v[j] = (__bf16)(acc2[tt][rq * 4 + j] + bv);
        *(bf16x4*)&xvT[(size_t)col * NROWS + m] = v;
      }
    } else {
      __bf16* dst = (mat == 0) ? xqb : xkb;
#pragma unroll
      for (int rq = 0; rq < 4; ++rq)
#pragma unroll
        for (int j = 0; j < 4; ++j) {
          int m = mrowbase + j + 8 * rq + 4 * g;
          dst[(size_t)m * DM + col] = (__bf16)((acc2[tt][rq * 4 + j] + bv) * oscale);
        }
    }
  }
}

// ---- flash staging (JB=32): K tile [32][256] + VT tile [256][32] ----
__device__ __forceinline__ void stage_tiles32(
    const __bf16* __restrict__ xkb, const __bf16* __restrict__ xvT,
    __bf16* Kbuf, __bf16* Vbuf, int j0, int w, int l) {
#pragma unroll
  for (int o = 0; o < 4; ++o) {
    int cbase = o * 256 + w * 64;
    int c = cbase + l;
    int j = c >> 5, kg = (c & 31) * 16;
    load_lds16((const char*)xkb + (size_t)(j0 + j) * 512 + (kg ^ ((j & 7) << 4)),
               (char*)Kbuf + (size_t)cbase * 16);
  }
#pragma unroll
  for (int o = 0; o < 4; ++o) {
    int cbase = o * 256 + w * 64;
    int c = cbase + l;
    int p = c ^ ((c >> 3) & 7);  // involution (bits>=3 unmodified)
    int v = p >> 2, jg = p & 3;
    load_lds16((const char*)xvT + (size_t)v * 16384 + (size_t)j0 * 2 + jg * 16,
               (char*)Vbuf + (size_t)cbase * 16);
  }
}

// ---- fused label-masked softmax-contrastive flash kernel ----
// Round-9 shape (JB=32, 2 blocks/CU, 4 waves = 2qh x 2vh, acc[4], S duplicated
// across the vh pair) + SPLIT SOFTMAX: each wave of a vh pair runs exp2/mask/
// cvt_pk on HALF of c (vh=0: r0..7 -> p0 frag; vh=1: r8..15 -> p1 frag) and
// the 16B fragments are exchanged through LDS (one extra barrier). Halves the
// duplicated VALU work with no added register pressure. Stats (half-j sums)
// are pair-combined in the epilogue.
__global__ __launch_bounds__(256, 2) void flash_kernel(
    const __bf16* __restrict__ xqb, const __bf16* __restrict__ xkb,
    const __bf16* __restrict__ xvT, const int* __restrict__ lab1,
    const int* __restrict__ lab2, __bf16* __restrict__ accp,
    float* __restrict__ sgp, float* __restrict__ psp) {
  __shared__ __align__(16) char smem[70656];
  __bf16* K_s0 = (__bf16*)smem;                // [2][32*256] = 32 KB
  __bf16* VT_s0 = (__bf16*)(smem + 32768);     // [2][256*32] = 32 KB
  unsigned* lpk = (unsigned*)(smem + 65536);   // 1 KB packed u8 labels (1024 j)
  uint4* Pex = (uint4*)(smem + 66560);         // 4 KB P-fragment exchange

  const int t = threadIdx.x;
  const int w = t >> 6, l = t & 63, g = l >> 5, l31 = l & 31;
  const int qh = w >> 1, vh = w & 1;
  const int f = blockIdx.x;
  const int js = f & 7;   // == XCD id under round-robin dispatch
  const int qb = f >> 3;  // 0..127
  const int j0base = js * 1024;

  {  // pack this chunk's labels as bytes (256 thr x 4 labels)
    int4 lv = *(const int4*)&lab2[j0base + t * 4];
    lpk[t] = (unsigned)(lv.x & 255) | ((unsigned)(lv.y & 255) << 8) |
             ((unsigned)(lv.z & 255) << 16) | ((unsigned)(lv.w & 255) << 24);
  }

  const int qrow = qb * 64 + qh * 32 + l31;
  bf16x8 qf[16];
#pragma unroll
  for (int ks = 0; ks < 16; ++ks)
    qf[ks] = *(const bf16x8*)&xqb[(size_t)qrow * DM + ks * 16 + g * 8];
  const unsigned lax = (unsigned)(lab1[qrow] & 255) * 0x01010101u;

  float s_p = 0.f, ps_p = 0.f;
  f32x16 acc[4];
#pragma unroll
  for (int tt = 0; tt < 4; ++tt) acc[tt] = fzero16();

  __syncthreads();  // lpk visible; prologue vmem drained (vmcnt==0)

  stage_tiles32(xkb, xvT, K_s0, VT_s0, j0base, w, l);                     // 0
  stage_tiles32(xkb, xvT, K_s0 + 8192, VT_s0 + 8192, j0base + 32, w, l);  // 1

  union PaU { unsigned uu[4]; bf16x8 v; };

#pragma unroll 1
  for (int it = 0; it < 32; ++it) {
    if (it < 31) {
      asm volatile("s_waitcnt vmcnt(8)" ::: "memory");  // stage(it) landed
    } else {
      asm volatile("s_waitcnt vmcnt(0)" ::: "memory");
    }
    __builtin_amdgcn_sched_barrier(0);
    __builtin_amdgcn_s_barrier();  // b_a
    __builtin_amdgcn_sched_barrier(0);

    const __bf16* Kc = K_s0 + (it & 1) * 8192;
    const __bf16* Vc = VT_s0 + (it & 1) * 8192;

    // ---- S = K@Q^T (32 j): c[j on regs][q on lanes] ----
    f32x16 c = fzero16();
    __builtin_amdgcn_s_setprio(1);
#pragma unroll
    for (int ks = 0; ks < 16; ++ks) {
      bf16x8 kb = *(const bf16x8*)&Kc[l31 * DM +
                                      ((ks * 16 + g * 8) ^ ((l31 & 7) << 3))];
      c = __builtin_amdgcn_mfma_f32_32x32x16_bf16(kb, qf[ks], c, 0, 0, 0);
    }
    __builtin_amdgcn_s_setprio(0);

    // ---- split softmax: own half of c -> own P-fragment ----
    const int rb = vh * 8;
    unsigned lb[2];
#pragma unroll
    for (int h = 0; h < 2; ++h)
      lb[h] = lpk[it * 8 + (vh * 2 + h) * 2 + g] ^ lax;
#pragma unroll
    for (int rr = 0; rr < 8; ++rr) {
      int r = rb + rr;
      float sv = c[r];
      float p = EXP2F(sv);
      s_p += p;
      bool mt = ((lb[rr >> 2] >> ((rr & 3) * 8)) & 255u) == 0u;
      ps_p += mt ? sv : 0.f;
      c[r] = mt ? p : 0.f;
    }
    unsigned u[4];
#pragma unroll
    for (int i = 0; i < 4; ++i)
      u[i] = cvtpk_bf16(c[rb + 2 * i], c[rb + 2 * i + 1]);
    swap32(u[0], u[2]); swap32(u[1], u[3]);
    uint4 own;
    own.x = u[0]; own.y = u[1]; own.z = u[2]; own.w = u[3];
    Pex[w * 64 + l] = own;
    asm volatile("s_waitcnt lgkmcnt(0)" ::: "memory");
    __builtin_amdgcn_sched_barrier(0);
    __builtin_amdgcn_s_barrier();  // b_p: fragments exchanged
    __builtin_amdgcn_sched_barrier(0);
    uint4 oth = Pex[(w ^ 1) * 64 + l];
    PaU p0, p1;
    p0.uu[0] = vh ? oth.x : own.x; p0.uu[1] = vh ? oth.y : own.y;
    p0.uu[2] = vh ? oth.z : own.z; p0.uu[3] = vh ? oth.w : own.w;
    p1.uu[0] = vh ? own.x : oth.x; p1.uu[1] = vh ? own.y : oth.y;
    p1.uu[2] = vh ? own.z : oth.z; p1.uu[3] = vh ? own.w : oth.w;

    // ---- PV: acc[32q on regs][128v on lanes] += P @ V (32 j) ----
    __builtin_amdgcn_s_setprio(1);
#pragma unroll
    for (int tt = 0; tt < 4; ++tt) {
      int v = vh * 128 + tt * 32 + l31;
#pragma unroll
      for (int kj = 0; kj < 2; ++kj) {
        int pg = v * 4 + kj * 2 + g;            // logical 16B granule
        int lg = pg ^ ((pg >> 3) & 7);          // swizzled LDS granule
        bf16x8 vb = *(const bf16x8*)&Vc[lg * 8];
        acc[tt] = __builtin_amdgcn_mfma_f32_32x32x16_bf16(
            kj ? p1.v : p0.v, vb, acc[tt], 0, 0, 0);
      }
    }
    __builtin_amdgcn_s_setprio(0);

    asm volatile("s_waitcnt lgkmcnt(0)" ::: "memory");
    __builtin_amdgcn_sched_barrier(0);
    __builtin_amdgcn_s_barrier();  // b_b: all waves done reading buf[it&1]
    __builtin_amdgcn_sched_barrier(0);
    if (it + 2 < 32)
      stage_tiles32(xkb, xvT, K_s0 + (it & 1) * 8192, VT_s0 + (it & 1) * 8192,
                    j0base + (it + 2) * 32, w, l);
  }

  // ---- epilogue: pair-combined stats + coalesced accp stores ----
  s_p += __shfl_xor(s_p, 32);
  ps_p += __shfl_xor(ps_p, 32);
  float* sred = (float*)(smem + 66560);  // reuse Pex space (loop done)
  if (l < 32) {
    sred[(w * 32 + l31) * 2] = s_p;
    sred[(w * 32 + l31) * 2 + 1] = ps_p;
  }
  __syncthreads();
  if (vh == 0 && l < 32) {
    float stot = s_p + sred[((w ^ 1) * 32 + l31) * 2];
    float ptot = ps_p + sred[((w ^ 1) * 32 + l31) * 2 + 1];
    sgp[(size_t)js * NROWS + qrow] = stot;
    psp[(size_t)js * NROWS + qrow] = ptot;
  }
  // stage acc (bf16) into padded LDS tile [64][264]
  __bf16* st = (__bf16*)smem;
#pragma unroll
  for (int tt = 0; tt < 4; ++tt)
#pragma unroll
    for (int r = 0; r < 16; ++r) {
      int row = qh * 32 + (r & 3) + 8 * (r >> 2) + 4 * g;
      int col = vh * 128 + tt * 32 + l31;
      st[row * 264 + col] = (__bf16)acc[tt][r];
    }
  __syncthreads();
  // linear copy LDS -> accp: 16B/lane, consecutive lanes -> consecutive 16B
  __bf16* dst = accp + ((size_t)js * NROWS + qb * 64) * DM;
#pragma unroll
  for (int p = 0; p < 8; ++p) {
    int off16 = p * 256 + t;   // 16B-granule index, 0..2047 (32 KB payload)
    int row = off16 >> 5;      // 32 granules (512 B) per row
    int colg = off16 & 31;
    bf16x8 v = *(const bf16x8*)&st[row * 264 + colg * 8];
    *(bf16x8*)&dst[(size_t)row * DM + colg * 8] = v;
  }
}

// ---- combine: sum 8 js partials; out=acc/s; res=x1+out; normalize; loss ----
__global__ __launch_bounds__(1024) void combine_kernel(
    const __bf16* __restrict__ accp, const float* __restrict__ sgp,
    const float* __restrict__ psp, const int* __restrict__ counts,
    const int* __restrict__ lab1, const float* __restrict__ x1,
    __bf16* __restrict__ resn, float* __restrict__ loss_out) {
  __shared__ float lred[16];
  const int t = threadIdx.x;
  const int rr = t >> 6;
  const int r = blockIdx.x * 16 + rr;
  const int l = t & 63;
  float s = 0.f;
#pragma unroll
  for (int js = 0; js < 8; ++js) s += sgp[(size_t)js * NROWS + r];
  const float inv = 1.f / s;
  float a0 = 0.f, a1 = 0.f, a2 = 0.f, a3 = 0.f;
#pragma unroll
  for (int js = 0; js < 8; ++js) {
    bf16x4 v = *(const bf16x4*)&accp[((size_t)js * NROWS + r) * DM + l * 4];
    a0 += (float)v[0]; a1 += (float)v[1]; a2 += (float)v[2]; a3 += (float)v[3];
  }
  float4 x = *(const float4*)&x1[(size_t)r * DM + l * 4];
  float o0 = x.x + a0 * inv, o1 = x.y + a1 * inv;
  float o2 = x.z + a2 * inv, o3 = x.w + a3 * inv;
  float sq = o0 * o0 + o1 * o1 + o2 * o2 + o3 * o3;
#pragma unroll
  for (int m = 1; m < 64; m <<= 1) sq += __shfl_xor(sq, m);
  const float nrm = 1.f / fmaxf(sqrtf(sq), 1e-12f);
  bf16x4 o;
  o[0] = (__bf16)(o0 * nrm); o[1] = (__bf16)(o1 * nrm);
  o[2] = (__bf16)(o2 * nrm); o[3] = (__bf16)(o3 * nrm);
  *(bf16x4*)&resn[(size_t)r * DM + l * 4] = o;
  if (l == 0) {
    float ps = 0.f;
#pragma unroll
    for (int js = 0; js < 8; ++js) ps += psp[(size_t)js * NROWS + r];
    float np = (float)counts[lab1[r] & 15];
    lred[rr] = (ps * LN2F - np * logf(s)) / fmaxf(np, 1.f);
  }
  __syncthreads();
  if (t == 0) {
    float accl = 0.f;
#pragma unroll
    for (int i = 0; i < 16; ++i) accl += lred[i];
    atomicAdd(loss_out, -accl * (1.f / 8192.f));
  }
}

// ---- final GEMM: out[m][n] = relu(resn@Wout + bout), scalar f32 stores ----
__global__ __launch_bounds__(256) void final_gemm(
    const __bf16* __restrict__ A, const __bf16* __restrict__ wmat,
    const float* __restrict__ bias, float* __restrict__ C) {
  __shared__ __bf16 W_s[64 * 256];
  const int t = threadIdx.x;
  const int w = t >> 6, l = t & 63, g = l >> 5, l31 = l & 31;
  const int mb = blockIdx.x, nt = blockIdx.y;
  const int n0 = nt * 64;
#pragma unroll
  for (int o = 0; o < 8; ++o) {
    int cbase = w * 64 + o * 256;
    int chunk = cbase + l;
    int n = chunk >> 5, kb = (chunk & 31) * 16;
    load_lds16((const char*)wmat + (size_t)(n0 + n) * 512 + (kb ^ ((n & 7) << 4)),
               (char*)W_s + (size_t)cbase * 16);
  }
  const int arow = mb * 128 + w * 32 + l31;
  bf16x8 af[16];
#pragma unroll
  for (int ks = 0; ks < 16; ++ks)
    af[ks] = *(const bf16x8*)&A[(size_t)arow * DM + ks * 16 + g * 8];
  __syncthreads();
  f32x16 acc2[2];
  acc2[0] = fzero16(); acc2[1] = fzero16();
#pragma unroll
  for (int ks = 0; ks < 16; ++ks)
#pragma unroll
    for (int tt = 0; tt < 2; ++tt) {
      int n = tt * 32 + l31;
      bf16x8 b = *(const bf16x8*)&W_s[n * DM + ((ks * 16 + g * 8) ^ ((n & 7) << 3))];
      acc2[tt] = __builtin_amdgcn_mfma_f32_32x32x16_bf16(af[ks], b, acc2[tt], 0, 0, 0);
    }
  const int mrowbase = mb * 128 + w * 32;
#pragma unroll
  for (int tt = 0; tt < 2; ++tt) {
    const int col = n0 + tt * 32 + l31;
    const float bv = bias[col];
#pragma unroll
    for (int rq = 0; rq < 4; ++rq)
#pragma unroll
      for (int j = 0; j < 4; ++j) {
        int m = mrowbase + j + 8 * rq + 4 * g;
        C[(size_t)m * DM + col] = fmaxf(acc2[tt][rq * 4 + j] + bv, 0.f);
      }
  }
}

extern "C" void kernel_launch(void* const* d_in, const int* in_sizes, int n_in,
                              void* d_out, int out_size, void* d_ws, size_t ws_size,
                              hipStream_t stream) {
  const float* x1 = (const float*)d_in[0];
  const float* x2 = (const float*)d_in[1];
  const int* lab1 = (const int*)d_in[2];
  const int* lab2 = (const int*)d_in[3];
  const float* Wxq = (const float*)d_in[4];
  const float* bxq = (const float*)d_in[5];
  const float* Wxk = (const float*)d_in[6];
  const float* bxk = (const float*)d_in[7];
  const float* Wxv = (const float*)d_in[8];
  const float* bxv = (const float*)d_in[9];
  const float* Wout = (const float*)d_in[10];
  const float* bout = (const float*)d_in[11];
  float* out = (float*)d_out;

  char* ws = (char*)d_ws;
  __bf16* xqb = (__bf16*)ws;                                // 4 MB
  __bf16* xkb = (__bf16*)(ws + (4 << 20));                  // 4 MB
  __bf16* xvT = (__bf16*)(ws + (8 << 20));                  // 4 MB [256][8192]
  __bf16* wt  = (__bf16*)(ws + (12 << 20));                 // 512 KB
  int* counts = (int*)(ws + (12 << 20) + (512 << 10));      // 64 B
  __bf16* accp = (__bf16*)(ws + (13 << 20));                // 32 MB [8][8192][256]
  float* sgp  = (float*)(ws + (45 << 20));                  // 256 KB [8][8192]
  float* psp  = (float*)(ws + (45 << 20) + (256 << 10));    // 256 KB
  __bf16* resn = xqb;  // alias: xqb dead after flash

  hipMemsetAsync(d_out, 0, sizeof(float), stream);  // loss accumulator only

  convert_w_kernel<<<dim3(64), dim3(256), 0, stream>>>(Wxq, Wxk, Wxv, Wout, wt);
  hist_kernel<<<dim3(1), dim3(1024), 0, stream>>>(lab2, counts);

  proj3_kernel<<<dim3(64, 4, 3), dim3(256), 0, stream>>>(
      x1, x2, wt, bxq, bxk, bxv, xqb, xkb, xvT);

  flash_kernel<<<dim3(1024), dim3(256), 0, stream>>>(
      xqb, xkb, xvT, lab1, lab2, accp, sgp, psp);

  combine_kernel<<<dim3(512), dim3(1024), 0, stream>>>(
      accp, sgp, psp, counts, lab1, x1, resn, out);

  final_gemm<<<dim3(64, 4), dim3(256), 0, stream>>>(resn, wt + 196608, bout,
                                                    out + 1);
}

// Round 13
// 167.590 us; speedup vs baseline: 1.9755x; 1.9755x over previous
//
#include <hip/hip_runtime.h>
#include <math.h>

#define DM 256
#define NROWS 8192
#define NCOLS 8192
#define LOG2E 1.44269504f
#define LN2F 0.6931471805599453f

typedef __attribute__((ext_vector_type(8)))  __bf16 bf16x8;
typedef __attribute__((ext_vector_type(4)))  __bf16 bf16x4;
typedef __attribute__((ext_vector_type(16))) float  f32x16;

#if __has_builtin(__builtin_amdgcn_exp2f)
#define EXP2F(x) __builtin_amdgcn_exp2f(x)
#else
#define EXP2F(x) exp2f(x)
#endif

__device__ __forceinline__ f32x16 fzero16() {
  f32x16 z;
#pragma unroll
  for (int i = 0; i < 16; ++i) z[i] = 0.f;
  return z;
}

__device__ __forceinline__ void load_lds16(const void* g, void* l) {
  __builtin_amdgcn_global_load_lds(
      (const __attribute__((address_space(1))) unsigned int*)g,
      (__attribute__((address_space(3))) unsigned int*)l, 16, 0, 0);
}

__device__ __forceinline__ bf16x8 cvt8(float4 a, float4 b) {
  bf16x8 v;
  v[0] = (__bf16)a.x; v[1] = (__bf16)a.y; v[2] = (__bf16)a.z; v[3] = (__bf16)a.w;
  v[4] = (__bf16)b.x; v[5] = (__bf16)b.y; v[6] = (__bf16)b.z; v[7] = (__bf16)b.w;
  return v;
}

__device__ __forceinline__ unsigned cvtpk_bf16(float lo, float hi) {
  unsigned r;
  asm("v_cvt_pk_bf16_f32 %0, %1, %2" : "=v"(r) : "v"(lo), "v"(hi));
  return r;
}
__device__ __forceinline__ void swap32(unsigned& a, unsigned& b) {
  asm("v_permlane32_swap_b32 %0, %1" : "+v"(a), "+v"(b));
}

// ---- prep: W transpose+cvt (blocks 0..63) + label hist + loss zero (64) ----
__global__ __launch_bounds__(256) void prep_kernel(
    const float* __restrict__ W0, const float* __restrict__ W1,
    const float* __restrict__ W2, const float* __restrict__ W3,
    __bf16* __restrict__ wt, const int* __restrict__ lab2,
    int* __restrict__ counts, float* __restrict__ loss_out) {
  const int t = threadIdx.x;
  if (blockIdx.x == 64) {
    __shared__ int h[16];
    if (t < 16) h[t] = 0;
    __syncthreads();
#pragma unroll
    for (int i = 0; i < 8; ++i) {
      int4 a = *(const int4*)&lab2[t * 32 + i * 4];
      atomicAdd(&h[a.x & 15], 1); atomicAdd(&h[a.y & 15], 1);
      atomicAdd(&h[a.z & 15], 1); atomicAdd(&h[a.w & 15], 1);
    }
    __syncthreads();
    if (t < 16) counts[t] = h[t];
    if (t == 0) *loss_out = 0.f;
    return;
  }
  __shared__ float Ls[64][65];
  const int mat = blockIdx.x >> 4;
  const int k0 = ((blockIdx.x >> 2) & 3) * 64;
  const int n0 = (blockIdx.x & 3) * 64;
  const float* W = mat == 0 ? W0 : mat == 1 ? W1 : mat == 2 ? W2 : W3;
#pragma unroll
  for (int i = 0; i < 4; ++i) {
    int idx = t + i * 256;
    int row = idx >> 4, c4 = (idx & 15) * 4;
    float4 v = *(const float4*)&W[(size_t)(k0 + row) * DM + n0 + c4];
    Ls[row][c4] = v.x; Ls[row][c4 + 1] = v.y;
    Ls[row][c4 + 2] = v.z; Ls[row][c4 + 3] = v.w;
  }
  __syncthreads();
#pragma unroll
  for (int i = 0; i < 2; ++i) {
    int c = t + i * 256;
    int n = c >> 3, kc = (c & 7) * 8;
    bf16x8 v;
#pragma unroll
    for (int j = 0; j < 8; ++j) v[j] = (__bf16)Ls[kc + j][n];
    *(bf16x8*)&wt[(size_t)mat * 65536 + (size_t)(n0 + n) * DM + k0 + kc] = v;
  }
}

// ---- fused 3-projection MFMA GEMM (grid.z = mat) ----
__global__ __launch_bounds__(256) void proj3_kernel(
    const float* __restrict__ x1, const float* __restrict__ x2,
    const __bf16* __restrict__ wt, const float* __restrict__ bxq,
    const float* __restrict__ bxk, const float* __restrict__ bxv,
    __bf16* __restrict__ xqb, __bf16* __restrict__ xkb,
    __bf16* __restrict__ xvT) {
  __shared__ __bf16 W_s[64 * 256];
  const int t = threadIdx.x;
  const int w = t >> 6, l = t & 63, g = l >> 5, l31 = l & 31;
  const int mb = blockIdx.x, nt = blockIdx.y, mat = blockIdx.z;
  const int n0 = nt * 64;
  const float* A = (mat == 0) ? x1 : x2;
  const __bf16* wmat = wt + (size_t)mat * 65536;
  const float* bias = (mat == 0) ? bxq : (mat == 1) ? bxk : bxv;
  const float oscale = (mat == 0) ? (0.0625f * LOG2E) : 1.0f;
#pragma unroll
  for (int o = 0; o < 8; ++o) {
    int cbase = w * 64 + o * 256;
    int chunk = cbase + l;
    int n = chunk >> 5, kb = (chunk & 31) * 16;
    load_lds16((const char*)wmat + (size_t)(n0 + n) * 512 + (kb ^ ((n & 7) << 4)),
               (char*)W_s + (size_t)cbase * 16);
  }
  const int arow = mb * 128 + w * 32 + l31;
  bf16x8 af[16];
#pragma unroll
  for (int ks = 0; ks < 16; ++ks) {
    float4 u0 = *(const float4*)&A[(size_t)arow * DM + ks * 16 + g * 8];
    float4 u1 = *(const float4*)&A[(size_t)arow * DM + ks * 16 + g * 8 + 4];
    af[ks] = cvt8(u0, u1);
  }
  __syncthreads();
  f32x16 acc2[2];
  acc2[0] = fzero16(); acc2[1] = fzero16();
#pragma unroll
  for (int ks = 0; ks < 16; ++ks)
#pragma unroll
    for (int tt = 0; tt < 2; ++tt) {
      int n = tt * 32 + l31;
      bf16x8 b = *(const bf16x8*)&W_s[n * DM + ((ks * 16 + g * 8) ^ ((n & 7) << 3))];
      acc2[tt] = __builtin_amdgcn_mfma_f32_32x32x16_bf16(af[ks], b, acc2[tt], 0, 0, 0);
    }
  const int mrowbase = mb * 128 + w * 32;
#pragma unroll
  for (int tt = 0; tt < 2; ++tt) {
    const int col = n0 + tt * 32 + l31;
    const float bv = bias[col];
    if (mat == 2) {
#pragma unroll
      for (int rq = 0; rq < 4; ++rq) {
        int m = mrowbase + 8 * rq + 4 * g;
        bf16x4 v;
#pragma unroll
        for (int j = 0; j < 4; ++j) v[j] = (__bf16)(acc2[tt][rq * 4 + j] + bv);
        *(bf16x4*)&xvT[(size_t)col * NROWS + m] = v;
      }
    } else {
      __bf16* dst = (mat == 0) ? xqb : xkb;
#pragma unroll
      for (int rq = 0; rq < 4; ++rq)
#pragma unroll
        for (int j = 0; j < 4; ++j) {
          int m = mrowbase + j + 8 * rq + 4 * g;
          dst[(size_t)m * DM + col] = (__bf16)((acc2[tt][rq * 4 + j] + bv) * oscale);
        }
    }
  }
}

// ---- flash staging (JB=32): K tile [32][256] + VT tile [256][32] ----
__device__ __forceinline__ void stage_tiles32(
    const __bf16* __restrict__ xkb, const __bf16* __restrict__ xvT,
    __bf16* Kbuf, __bf16* Vbuf, int j0, int w, int l) {
#pragma unroll
  for (int o = 0; o < 4; ++o) {
    int cbase = o * 256 + w * 64;
    int c = cbase + l;
    int j = c >> 5, kg = (c & 31) * 16;
    load_lds16((const char*)xkb + (size_t)(j0 + j) * 512 + (kg ^ ((j & 7) << 4)),
               (char*)Kbuf + (size_t)cbase * 16);
  }
#pragma unroll
  for (int o = 0; o < 4; ++o) {
    int cbase = o * 256 + w * 64;
    int c = cbase + l;
    int p = c ^ ((c >> 3) & 7);  // involution (bits>=3 unmodified)
    int v = p >> 2, jg = p & 3;
    load_lds16((const char*)xvT + (size_t)v * 16384 + (size_t)j0 * 2 + jg * 16,
               (char*)Vbuf + (size_t)cbase * 16);
  }
}

// ---- fused label-masked softmax-contrastive flash kernel (round-9 shape) ----
// JB=32, 65 KB LDS -> 2 blocks/CU. 4 waves = 2qh x 2vh; S duplicated across
// the vh pair (P stays in registers, acc[4], ~190 live regs, no spill).
// STAT-SPLIT: each wave accumulates s_p/ps_p only for its j-half
// ((r>>3)==vh, compile-time predicate); pair-combined in the epilogue via
// LDS (reuses dead lpk space). No change to loop barriers or data flow.
__global__ __launch_bounds__(256, 2) void flash_kernel(
    const __bf16* __restrict__ xqb, const __bf16* __restrict__ xkb,
    const __bf16* __restrict__ xvT, const int* __restrict__ lab1,
    const int* __restrict__ lab2, __bf16* __restrict__ accp,
    float* __restrict__ sgp, float* __restrict__ psp) {
  __shared__ __align__(16) char smem[66560];
  __bf16* K_s0 = (__bf16*)smem;                // [2][32*256] = 32 KB
  __bf16* VT_s0 = (__bf16*)(smem + 32768);     // [2][256*32] = 32 KB
  unsigned* lpk = (unsigned*)(smem + 65536);   // 1 KB packed u8 labels (1024 j)

  const int t = threadIdx.x;
  const int w = t >> 6, l = t & 63, g = l >> 5, l31 = l & 31;
  const int qh = w >> 1, vh = w & 1;
  const int f = blockIdx.x;
  const int js = f & 7;   // == XCD id under round-robin dispatch
  const int qb = f >> 3;  // 0..127
  const int j0base = js * 1024;

  {  // pack this chunk's labels as bytes (256 thr x 4 labels)
    int4 lv = *(const int4*)&lab2[j0base + t * 4];
    lpk[t] = (unsigned)(lv.x & 255) | ((unsigned)(lv.y & 255) << 8) |
             ((unsigned)(lv.z & 255) << 16) | ((unsigned)(lv.w & 255) << 24);
  }

  const int qrow = qb * 64 + qh * 32 + l31;
  bf16x8 qf[16];
#pragma unroll
  for (int ks = 0; ks < 16; ++ks)
    qf[ks] = *(const bf16x8*)&xqb[(size_t)qrow * DM + ks * 16 + g * 8];
  const unsigned lax = (unsigned)(lab1[qrow] & 255) * 0x01010101u;

  float s_p = 0.f, ps_p = 0.f;
  f32x16 acc[4];
#pragma unroll
  for (int tt = 0; tt < 4; ++tt) acc[tt] = fzero16();

  __syncthreads();  // lpk visible; prologue vmem drained (vmcnt==0)

  stage_tiles32(xkb, xvT, K_s0, VT_s0, j0base, w, l);                     // 0
  stage_tiles32(xkb, xvT, K_s0 + 8192, VT_s0 + 8192, j0base + 32, w, l);  // 1

  union PaU { unsigned uu[4]; bf16x8 v; };

#pragma unroll 1
  for (int it = 0; it < 32; ++it) {
    if (it < 31) {
      asm volatile("s_waitcnt vmcnt(8)" ::: "memory");  // stage(it) landed
    } else {
      asm volatile("s_waitcnt vmcnt(0)" ::: "memory");
    }
    __builtin_amdgcn_sched_barrier(0);
    __builtin_amdgcn_s_barrier();
    __builtin_amdgcn_sched_barrier(0);

    const __bf16* Kc = K_s0 + (it & 1) * 8192;
    const __bf16* Vc = VT_s0 + (it & 1) * 8192;

    // ---- S = K@Q^T (32 j): c[j on regs][q on lanes] ----
    f32x16 c = fzero16();
    __builtin_amdgcn_s_setprio(1);
#pragma unroll
    for (int ks = 0; ks < 16; ++ks) {
      bf16x8 kb = *(const bf16x8*)&Kc[l31 * DM +
                                      ((ks * 16 + g * 8) ^ ((l31 & 7) << 3))];
      c = __builtin_amdgcn_mfma_f32_32x32x16_bf16(kb, qf[ks], c, 0, 0, 0);
    }
    __builtin_amdgcn_s_setprio(0);

    // ---- softmax + mask (c = 1.4427*S; exp2); stats for own j-half only ----
    unsigned lb[4];
#pragma unroll
    for (int q4 = 0; q4 < 4; ++q4)
      lb[q4] = lpk[it * 8 + q4 * 2 + g] ^ lax;
#pragma unroll
    for (int r = 0; r < 16; ++r) {
      float sv = c[r];
      float p = EXP2F(sv);
      bool mt = ((lb[r >> 2] >> ((r & 3) * 8)) & 255u) == 0u;
      if ((r >> 3) == vh) {  // compile-time predicate per unrolled r
        s_p += p;
        ps_p += mt ? sv : 0.f;
      }
      c[r] = mt ? p : 0.f;
    }
    unsigned u[8];
#pragma unroll
    for (int i = 0; i < 8; ++i) u[i] = cvtpk_bf16(c[2 * i], c[2 * i + 1]);
    swap32(u[0], u[2]); swap32(u[1], u[3]);
    swap32(u[4], u[6]); swap32(u[5], u[7]);
    PaU p0, p1;
    p0.uu[0] = u[0]; p0.uu[1] = u[1]; p0.uu[2] = u[2]; p0.uu[3] = u[3];
    p1.uu[0] = u[4]; p1.uu[1] = u[5]; p1.uu[2] = u[6]; p1.uu[3] = u[7];

    // ---- PV: acc[32q on regs][128v on lanes] += P @ V (32 j) ----
    __builtin_amdgcn_s_setprio(1);
#pragma unroll
    for (int tt = 0; tt < 4; ++tt) {
      int v = vh * 128 + tt * 32 + l31;
#pragma unroll
      for (int kj = 0; kj < 2; ++kj) {
        int pg = v * 4 + kj * 2 + g;            // logical 16B granule
        int lg = pg ^ ((pg >> 3) & 7);          // swizzled LDS granule
        bf16x8 vb = *(const bf16x8*)&Vc[lg * 8];
        acc[tt] = __builtin_amdgcn_mfma_f32_32x32x16_bf16(
            kj ? p1.v : p0.v, vb, acc[tt], 0, 0, 0);
      }
    }
    __builtin_amdgcn_s_setprio(0);

    asm volatile("s_waitcnt lgkmcnt(0)" ::: "memory");
    __builtin_amdgcn_sched_barrier(0);
    __builtin_amdgcn_s_barrier();  // all waves done reading buf[it&1]
    __builtin_amdgcn_sched_barrier(0);
    if (it + 2 < 32)
      stage_tiles32(xkb, xvT, K_s0 + (it & 1) * 8192, VT_s0 + (it & 1) * 8192,
                    j0base + (it + 2) * 32, w, l);
  }

  // ---- epilogue: pair-combine stats (lpk space is dead) + accp stores ----
  s_p += __shfl_xor(s_p, 32);
  ps_p += __shfl_xor(ps_p, 32);
  float* sred = (float*)(smem + 65536);  // 4 waves x 32 x 2 f32 = 1 KB
  if (l < 32) {
    sred[(w * 32 + l31) * 2] = s_p;
    sred[(w * 32 + l31) * 2 + 1] = ps_p;
  }
  __syncthreads();
  if (vh == 0 && l < 32) {
    float stot = s_p + sred[(((w ^ 1) * 32) + l31) * 2];
    float ptot = ps_p + sred[(((w ^ 1) * 32) + l31) * 2 + 1];
    sgp[(size_t)js * NROWS + qrow] = stot;
    psp[(size_t)js * NROWS + qrow] = ptot;
  }
  // stage acc (bf16) into padded LDS tile [64][264]
  __bf16* st = (__bf16*)smem;
#pragma unroll
  for (int tt = 0; tt < 4; ++tt)
#pragma unroll
    for (int r = 0; r < 16; ++r) {
      int row = qh * 32 + (r & 3) + 8 * (r >> 2) + 4 * g;
      int col = vh * 128 + tt * 32 + l31;
      st[row * 264 + col] = (__bf16)acc[tt][r];
    }
  __syncthreads();
  // linear copy LDS -> accp: 16B/lane, consecutive lanes -> consecutive 16B
  __bf16* dst = accp + ((size_t)js * NROWS + qb * 64) * DM;
#pragma unroll
  for (int p = 0; p < 8; ++p) {
    int off16 = p * 256 + t;   // 16B-granule index, 0..2047 (32 KB payload)
    int row = off16 >> 5;      // 32 granules (512 B) per row
    int colg = off16 & 31;
    bf16x8 v = *(const bf16x8*)&st[row * 264 + colg * 8];
    *(bf16x8*)&dst[(size_t)row * DM + colg * 8] = v;
  }
}

// ---- combine: sum 8 js partials; out=acc/s; res=x1+out; normalize; loss ----
__global__ __launch_bounds__(1024) void combine_kernel(
    const __bf16* __restrict__ accp, const float* __restrict__ sgp,
    const float* __restrict__ psp, const int* __restrict__ counts,
    const int* __restrict__ lab1, const float* __restrict__ x1,
    __bf16* __restrict__ resn, float* __restrict__ loss_out) {
  __shared__ float lred[16];
  const int t = threadIdx.x;
  const int rr = t >> 6;
  const int r = blockIdx.x * 16 + rr;
  const int l = t & 63;
  float s = 0.f;
#pragma unroll
  for (int js = 0; js < 8; ++js) s += sgp[(size_t)js * NROWS + r];
  const float inv = 1.f / s;
  float a0 = 0.f, a1 = 0.f, a2 = 0.f, a3 = 0.f;
#pragma unroll
  for (int js = 0; js < 8; ++js) {
    bf16x4 v = *(const bf16x4*)&accp[((size_t)js * NROWS + r) * DM + l * 4];
    a0 += (float)v[0]; a1 += (float)v[1]; a2 += (float)v[2]; a3 += (float)v[3];
  }
  float4 x = *(const float4*)&x1[(size_t)r * DM + l * 4];
  float o0 = x.x + a0 * inv, o1 = x.y + a1 * inv;
  float o2 = x.z + a2 * inv, o3 = x.w + a3 * inv;
  float sq = o0 * o0 + o1 * o1 + o2 * o2 + o3 * o3;
#pragma unroll
  for (int m = 1; m < 64; m <<= 1) sq += __shfl_xor(sq, m);
  const float nrm = 1.f / fmaxf(sqrtf(sq), 1e-12f);
  bf16x4 o;
  o[0] = (__bf16)(o0 * nrm); o[1] = (__bf16)(o1 * nrm);
  o[2] = (__bf16)(o2 * nrm); o[3] = (__bf16)(o3 * nrm);
  *(bf16x4*)&resn[(size_t)r * DM + l * 4] = o;
  if (l == 0) {
    float ps = 0.f;
#pragma unroll
    for (int js = 0; js < 8; ++js) ps += psp[(size_t)js * NROWS + r];
    float np = (float)counts[lab1[r] & 15];
    lred[rr] = (ps * LN2F - np * logf(s)) / fmaxf(np, 1.f);
  }
  __syncthreads();
  if (t == 0) {
    float accl = 0.f;
#pragma unroll
    for (int i = 0; i < 16; ++i) accl += lred[i];
    atomicAdd(loss_out, -accl * (1.f / 8192.f));
  }
}

// ---- final GEMM: out[m][n] = relu(resn@Wout + bout), scalar f32 stores ----
__global__ __launch_bounds__(256) void final_gemm(
    const __bf16* __restrict__ A, const __bf16* __restrict__ wmat,
    const float* __restrict__ bias, float* __restrict__ C) {
  __shared__ __bf16 W_s[64 * 256];
  const int t = threadIdx.x;
  const int w = t >> 6, l = t & 63, g = l >> 5, l31 = l & 31;
  const int mb = blockIdx.x, nt = blockIdx.y;
  const int n0 = nt * 64;
#pragma unroll
  for (int o = 0; o < 8; ++o) {
    int cbase = w * 64 + o * 256;
    int chunk = cbase + l;
    int n = chunk >> 5, kb = (chunk & 31) * 16;
    load_lds16((const char*)wmat + (size_t)(n0 + n) * 512 + (kb ^ ((n & 7) << 4)),
               (char*)W_s + (size_t)cbase * 16);
  }
  const int arow = mb * 128 + w * 32 + l31;
  bf16x8 af[16];
#pragma unroll
  for (int ks = 0; ks < 16; ++ks)
    af[ks] = *(const bf16x8*)&A[(size_t)arow * DM + ks * 16 + g * 8];
  __syncthreads();
  f32x16 acc2[2];
  acc2[0] = fzero16(); acc2[1] = fzero16();
#pragma unroll
  for (int ks = 0; ks < 16; ++ks)
#pragma unroll
    for (int tt = 0; tt < 2; ++tt) {
      int n = tt * 32 + l31;
      bf16x8 b = *(const bf16x8*)&W_s[n * DM + ((ks * 16 + g * 8) ^ ((n & 7) << 3))];
      acc2[tt] = __builtin_amdgcn_mfma_f32_32x32x16_bf16(af[ks], b, acc2[tt], 0, 0, 0);
    }
  const int mrowbase = mb * 128 + w * 32;
#pragma unroll
  for (int tt = 0; tt < 2; ++tt) {
    const int col = n0 + tt * 32 + l31;
    const float bv = bias[col];
#pragma unroll
    for (int rq = 0; rq < 4; ++rq)
#pragma unroll
      for (int j = 0; j < 4; ++j) {
        int m = mrowbase + j + 8 * rq + 4 * g;
        C[(size_t)m * DM + col] = fmaxf(acc2[tt][rq * 4 + j] + bv, 0.f);
      }
  }
}

extern "C" void kernel_launch(void* const* d_in, const int* in_sizes, int n_in,
                              void* d_out, int out_size, void* d_ws, size_t ws_size,
                              hipStream_t stream) {
  const float* x1 = (const float*)d_in[0];
  const float* x2 = (const float*)d_in[1];
  const int* lab1 = (const int*)d_in[2];
  const int* lab2 = (const int*)d_in[3];
  const float* Wxq = (const float*)d_in[4];
  const float* bxq = (const float*)d_in[5];
  const float* Wxk = (const float*)d_in[6];
  const float* bxk = (const float*)d_in[7];
  const float* Wxv = (const float*)d_in[8];
  const float* bxv = (const float*)d_in[9];
  const float* Wout = (const float*)d_in[10];
  const float* bout = (const float*)d_in[11];
  float* out = (float*)d_out;

  char* ws = (char*)d_ws;
  __bf16* xqb = (__bf16*)ws;                                // 4 MB
  __bf16* xkb = (__bf16*)(ws + (4 << 20));                  // 4 MB
  __bf16* xvT = (__bf16*)(ws + (8 << 20));                  // 4 MB [256][8192]
  __bf16* wt  = (__bf16*)(ws + (12 << 20));                 // 512 KB
  int* counts = (int*)(ws + (12 << 20) + (512 << 10));      // 64 B
  __bf16* accp = (__bf16*)(ws + (13 << 20));                // 32 MB [8][8192][256]
  float* sgp  = (float*)(ws + (45 << 20));                  // 256 KB [8][8192]
  float* psp  = (float*)(ws + (45 << 20) + (256 << 10));    // 256 KB
  __bf16* resn = xqb;  // alias: xqb dead after flash

  prep_kernel<<<dim3(65), dim3(256), 0, stream>>>(Wxq, Wxk, Wxv, Wout, wt,
                                                  lab2, counts, out);

  proj3_kernel<<<dim3(64, 4, 3), dim3(256), 0, stream>>>(
      x1, x2, wt, bxq, bxk, bxv, xqb, xkb, xvT);

  flash_kernel<<<dim3(1024), dim3(256), 0, stream>>>(
      xqb, xkb, xvT, lab1, lab2, accp, sgp, psp);

  combine_kernel<<<dim3(512), dim3(1024), 0, stream>>>(
      accp, sgp, psp, counts, lab1, x1, resn, out);

  final_gemm<<<dim3(64, 4), dim3(256), 0, stream>>>(resn, wt + 196608, bout,
                                                    out + 1);
}

// Round 14
// 164.653 us; speedup vs baseline: 2.0107x; 1.0178x over previous
//
#include <hip/hip_runtime.h>
#include <math.h>

#define DM 256
#define NROWS 8192
#define NCOLS 8192
#define JSPLIT 4
#define LOG2E 1.44269504f
#define LN2F 0.6931471805599453f

typedef __attribute__((ext_vector_type(8)))  __bf16 bf16x8;
typedef __attribute__((ext_vector_type(4)))  __bf16 bf16x4;
typedef __attribute__((ext_vector_type(16))) float  f32x16;

#if __has_builtin(__builtin_amdgcn_exp2f)
#define EXP2F(x) __builtin_amdgcn_exp2f(x)
#else
#define EXP2F(x) exp2f(x)
#endif

__device__ __forceinline__ f32x16 fzero16() {
  f32x16 z;
#pragma unroll
  for (int i = 0; i < 16; ++i) z[i] = 0.f;
  return z;
}

__device__ __forceinline__ void load_lds16(const void* g, void* l) {
  __builtin_amdgcn_global_load_lds(
      (const __attribute__((address_space(1))) unsigned int*)g,
      (__attribute__((address_space(3))) unsigned int*)l, 16, 0, 0);
}

__device__ __forceinline__ bf16x8 cvt8(float4 a, float4 b) {
  bf16x8 v;
  v[0] = (__bf16)a.x; v[1] = (__bf16)a.y; v[2] = (__bf16)a.z; v[3] = (__bf16)a.w;
  v[4] = (__bf16)b.x; v[5] = (__bf16)b.y; v[6] = (__bf16)b.z; v[7] = (__bf16)b.w;
  return v;
}

__device__ __forceinline__ unsigned cvtpk_bf16(float lo, float hi) {
  unsigned r;
  asm("v_cvt_pk_bf16_f32 %0, %1, %2" : "=v"(r) : "v"(lo), "v"(hi));
  return r;
}
__device__ __forceinline__ void swap32(unsigned& a, unsigned& b) {
  asm("v_permlane32_swap_b32 %0, %1" : "+v"(a), "+v"(b));
}

// ---- prep: W transpose+cvt (blocks 0..63) + label hist + loss zero (64) ----
__global__ __launch_bounds__(256) void prep_kernel(
    const float* __restrict__ W0, const float* __restrict__ W1,
    const float* __restrict__ W2, const float* __restrict__ W3,
    __bf16* __restrict__ wt, const int* __restrict__ lab2,
    int* __restrict__ counts, float* __restrict__ loss_out) {
  const int t = threadIdx.x;
  if (blockIdx.x == 64) {
    __shared__ int h[16];
    if (t < 16) h[t] = 0;
    __syncthreads();
#pragma unroll
    for (int i = 0; i < 8; ++i) {
      int4 a = *(const int4*)&lab2[t * 32 + i * 4];
      atomicAdd(&h[a.x & 15], 1); atomicAdd(&h[a.y & 15], 1);
      atomicAdd(&h[a.z & 15], 1); atomicAdd(&h[a.w & 15], 1);
    }
    __syncthreads();
    if (t < 16) counts[t] = h[t];
    if (t == 0) *loss_out = 0.f;
    return;
  }
  __shared__ float Ls[64][65];
  const int mat = blockIdx.x >> 4;
  const int k0 = ((blockIdx.x >> 2) & 3) * 64;
  const int n0 = (blockIdx.x & 3) * 64;
  const float* W = mat == 0 ? W0 : mat == 1 ? W1 : mat == 2 ? W2 : W3;
#pragma unroll
  for (int i = 0; i < 4; ++i) {
    int idx = t + i * 256;
    int row = idx >> 4, c4 = (idx & 15) * 4;
    float4 v = *(const float4*)&W[(size_t)(k0 + row) * DM + n0 + c4];
    Ls[row][c4] = v.x; Ls[row][c4 + 1] = v.y;
    Ls[row][c4 + 2] = v.z; Ls[row][c4 + 3] = v.w;
  }
  __syncthreads();
#pragma unroll
  for (int i = 0; i < 2; ++i) {
    int c = t + i * 256;
    int n = c >> 3, kc = (c & 7) * 8;
    bf16x8 v;
#pragma unroll
    for (int j = 0; j < 8; ++j) v[j] = (__bf16)Ls[kc + j][n];
    *(bf16x8*)&wt[(size_t)mat * 65536 + (size_t)(n0 + n) * DM + k0 + kc] = v;
  }
}

// ---- fused 3-projection MFMA GEMM (grid (64,1,3); internal n-tile loop:
// A-fragments loaded ONCE into registers, W tile re-staged per n-tile ->
// A HBM traffic 96 MB -> 24 MB) ----
__global__ __launch_bounds__(256) void proj3_kernel(
    const float* __restrict__ x1, const float* __restrict__ x2,
    const __bf16* __restrict__ wt, const float* __restrict__ bxq,
    const float* __restrict__ bxk, const float* __restrict__ bxv,
    __bf16* __restrict__ xqb, __bf16* __restrict__ xkb,
    __bf16* __restrict__ xvT) {
  __shared__ __bf16 W_s[64 * 256];
  const int t = threadIdx.x;
  const int w = t >> 6, l = t & 63, g = l >> 5, l31 = l & 31;
  const int mb = blockIdx.x, mat = blockIdx.z;
  const float* A = (mat == 0) ? x1 : x2;
  const __bf16* wmat = wt + (size_t)mat * 65536;
  const float* bias = (mat == 0) ? bxq : (mat == 1) ? bxk : bxv;
  const float oscale = (mat == 0) ? (0.0625f * LOG2E) : 1.0f;
  const int arow = mb * 128 + w * 32 + l31;
  bf16x8 af[16];
#pragma unroll
  for (int ks = 0; ks < 16; ++ks) {
    float4 u0 = *(const float4*)&A[(size_t)arow * DM + ks * 16 + g * 8];
    float4 u1 = *(const float4*)&A[(size_t)arow * DM + ks * 16 + g * 8 + 4];
    af[ks] = cvt8(u0, u1);
  }
  const int mrowbase = mb * 128 + w * 32;
#pragma unroll 1
  for (int nt = 0; nt < 4; ++nt) {
    const int n0 = nt * 64;
#pragma unroll
    for (int o = 0; o < 8; ++o) {
      int cbase = w * 64 + o * 256;
      int chunk = cbase + l;
      int n = chunk >> 5, kb = (chunk & 31) * 16;
      load_lds16((const char*)wmat + (size_t)(n0 + n) * 512 + (kb ^ ((n & 7) << 4)),
                 (char*)W_s + (size_t)cbase * 16);
    }
    __syncthreads();  // staging landed (implicit vmcnt drain)
    f32x16 acc2[2];
    acc2[0] = fzero16(); acc2[1] = fzero16();
#pragma unroll
    for (int ks = 0; ks < 16; ++ks)
#pragma unroll
      for (int tt = 0; tt < 2; ++tt) {
        int n = tt * 32 + l31;
        bf16x8 b = *(const bf16x8*)&W_s[n * DM + ((ks * 16 + g * 8) ^ ((n & 7) << 3))];
        acc2[tt] = __builtin_amdgcn_mfma_f32_32x32x16_bf16(af[ks], b, acc2[tt], 0, 0, 0);
      }
#pragma unroll
    for (int tt = 0; tt < 2; ++tt) {
      const int col = n0 + tt * 32 + l31;
      const float bv = bias[col];
      if (mat == 2) {
#pragma unroll
        for (int rq = 0; rq < 4; ++rq) {
          int m = mrowbase + 8 * rq + 4 * g;
          bf16x4 v;
#pragma unroll
          for (int j = 0; j < 4; ++j) v[j] = (__bf16)(acc2[tt][rq * 4 + j] + bv);
          *(bf16x4*)&xvT[(size_t)col * NROWS + m] = v;
        }
      } else {
        __bf16* dst = (mat == 0) ? xqb : xkb;
#pragma unroll
        for (int rq = 0; rq < 4; ++rq)
#pragma unroll
          for (int j = 0; j < 4; ++j) {
            int m = mrowbase + j + 8 * rq + 4 * g;
            dst[(size_t)m * DM + col] = (__bf16)((acc2[tt][rq * 4 + j] + bv) * oscale);
          }
      }
    }
    __syncthreads();  // all waves done reading W_s before next stage
  }
}

// ---- flash staging (JB=32): K tile [32][256] + VT tile [256][32] ----
__device__ __forceinline__ void stage_tiles32(
    const __bf16* __restrict__ xkb, const __bf16* __restrict__ xvT,
    __bf16* Kbuf, __bf16* Vbuf, int j0, int w, int l) {
#pragma unroll
  for (int o = 0; o < 4; ++o) {
    int cbase = o * 256 + w * 64;
    int c = cbase + l;
    int j = c >> 5, kg = (c & 31) * 16;
    load_lds16((const char*)xkb + (size_t)(j0 + j) * 512 + (kg ^ ((j & 7) << 4)),
               (char*)Kbuf + (size_t)cbase * 16);
  }
#pragma unroll
  for (int o = 0; o < 4; ++o) {
    int cbase = o * 256 + w * 64;
    int c = cbase + l;
    int p = c ^ ((c >> 3) & 7);  // involution (bits>=3 unmodified)
    int v = p >> 2, jg = p & 3;
    load_lds16((const char*)xvT + (size_t)v * 16384 + (size_t)j0 * 2 + jg * 16,
               (char*)Vbuf + (size_t)cbase * 16);
  }
}

// ---- fused label-masked softmax-contrastive flash kernel (round-9 shape) ----
// JSPLIT=4: grid 512 = EXACTLY 2 blocks/CU in one residency round (no second
// round tail). js = f&3 (each XCD serves one 2 MB K/V chunk: (f&7)&3 const
// per XCD). 64 iters/block. Loop body identical to the validated r9/r13 loop.
__global__ __launch_bounds__(256, 2) void flash_kernel(
    const __bf16* __restrict__ xqb, const __bf16* __restrict__ xkb,
    const __bf16* __restrict__ xvT, const int* __restrict__ lab1,
    const int* __restrict__ lab2, __bf16* __restrict__ accp,
    float* __restrict__ sgp, float* __restrict__ psp) {
  __shared__ __align__(16) char smem[67584];
  __bf16* K_s0 = (__bf16*)smem;                // [2][32*256] = 32 KB
  __bf16* VT_s0 = (__bf16*)(smem + 32768);     // [2][256*32] = 32 KB
  unsigned* lpk = (unsigned*)(smem + 65536);   // 2 KB packed u8 labels (2048 j)

  const int t = threadIdx.x;
  const int w = t >> 6, l = t & 63, g = l >> 5, l31 = l & 31;
  const int qh = w >> 1, vh = w & 1;
  const int f = blockIdx.x;
  const int js = f & 3;   // one chunk per XCD under round-robin
  const int qb = f >> 2;  // 0..127
  const int j0base = js * 2048;

  {  // pack this chunk's labels as bytes (256 thr x 8 labels)
#pragma unroll
    for (int i = 0; i < 2; ++i) {
      int idx = t * 2 + i;
      int4 lv = *(const int4*)&lab2[j0base + idx * 4];
      lpk[idx] = (unsigned)(lv.x & 255) | ((unsigned)(lv.y & 255) << 8) |
                 ((unsigned)(lv.z & 255) << 16) | ((unsigned)(lv.w & 255) << 24);
    }
  }

  const int qrow = qb * 64 + qh * 32 + l31;
  bf16x8 qf[16];
#pragma unroll
  for (int ks = 0; ks < 16; ++ks)
    qf[ks] = *(const bf16x8*)&xqb[(size_t)qrow * DM + ks * 16 + g * 8];
  const unsigned lax = (unsigned)(lab1[qrow] & 255) * 0x01010101u;

  float s_p = 0.f, ps_p = 0.f;
  f32x16 acc[4];
#pragma unroll
  for (int tt = 0; tt < 4; ++tt) acc[tt] = fzero16();

  __syncthreads();  // lpk visible; prologue vmem drained (vmcnt==0)

  stage_tiles32(xkb, xvT, K_s0, VT_s0, j0base, w, l);                     // 0
  stage_tiles32(xkb, xvT, K_s0 + 8192, VT_s0 + 8192, j0base + 32, w, l);  // 1

  union PaU { unsigned uu[4]; bf16x8 v; };

#pragma unroll 1
  for (int it = 0; it < 64; ++it) {
    if (it < 63) {
      asm volatile("s_waitcnt vmcnt(8)" ::: "memory");  // stage(it) landed
    } else {
      asm volatile("s_waitcnt vmcnt(0)" ::: "memory");
    }
    __builtin_amdgcn_sched_barrier(0);
    __builtin_amdgcn_s_barrier();
    __builtin_amdgcn_sched_barrier(0);

    const __bf16* Kc = K_s0 + (it & 1) * 8192;
    const __bf16* Vc = VT_s0 + (it & 1) * 8192;

    // ---- S = K@Q^T (32 j): c[j on regs][q on lanes] ----
    f32x16 c = fzero16();
    __builtin_amdgcn_s_setprio(1);
#pragma unroll
    for (int ks = 0; ks < 16; ++ks) {
      bf16x8 kb = *(const bf16x8*)&Kc[l31 * DM +
                                      ((ks * 16 + g * 8) ^ ((l31 & 7) << 3))];
      c = __builtin_amdgcn_mfma_f32_32x32x16_bf16(kb, qf[ks], c, 0, 0, 0);
    }
    __builtin_amdgcn_s_setprio(0);

    // ---- softmax + mask (c = 1.4427*S; exp2); stats for own j-half ----
    unsigned lb[4];
#pragma unroll
    for (int q4 = 0; q4 < 4; ++q4)
      lb[q4] = lpk[it * 8 + q4 * 2 + g] ^ lax;
#pragma unroll
    for (int r = 0; r < 16; ++r) {
      float sv = c[r];
      float p = EXP2F(sv);
      bool mt = ((lb[r >> 2] >> ((r & 3) * 8)) & 255u) == 0u;
      if ((r >> 3) == vh) {  // compile-time predicate per unrolled r
        s_p += p;
        ps_p += mt ? sv : 0.f;
      }
      c[r] = mt ? p : 0.f;
    }
    unsigned u[8];
#pragma unroll
    for (int i = 0; i < 8; ++i) u[i] = cvtpk_bf16(c[2 * i], c[2 * i + 1]);
    swap32(u[0], u[2]); swap32(u[1], u[3]);
    swap32(u[4], u[6]); swap32(u[5], u[7]);
    PaU p0, p1;
    p0.uu[0] = u[0]; p0.uu[1] = u[1]; p0.uu[2] = u[2]; p0.uu[3] = u[3];
    p1.uu[0] = u[4]; p1.uu[1] = u[5]; p1.uu[2] = u[6]; p1.uu[3] = u[7];

    // ---- PV: acc[32q on regs][128v on lanes] += P @ V (32 j) ----
    __builtin_amdgcn_s_setprio(1);
#pragma unroll
    for (int tt = 0; tt < 4; ++tt) {
      int v = vh * 128 + tt * 32 + l31;
#pragma unroll
      for (int kj = 0; kj < 2; ++kj) {
        int pg = v * 4 + kj * 2 + g;            // logical 16B granule
        int lg = pg ^ ((pg >> 3) & 7);          // swizzled LDS granule
        bf16x8 vb = *(const bf16x8*)&Vc[lg * 8];
        acc[tt] = __builtin_amdgcn_mfma_f32_32x32x16_bf16(
            kj ? p1.v : p0.v, vb, acc[tt], 0, 0, 0);
      }
    }
    __builtin_amdgcn_s_setprio(0);

    asm volatile("s_waitcnt lgkmcnt(0)" ::: "memory");
    __builtin_amdgcn_sched_barrier(0);
    __builtin_amdgcn_s_barrier();  // all waves done reading buf[it&1]
    __builtin_amdgcn_sched_barrier(0);
    if (it + 2 < 64)
      stage_tiles32(xkb, xvT, K_s0 + (it & 1) * 8192, VT_s0 + (it & 1) * 8192,
                    j0base + (it + 2) * 32, w, l);
  }

  // ---- epilogue: pair-combine stats (lpk space dead) + accp stores ----
  s_p += __shfl_xor(s_p, 32);
  ps_p += __shfl_xor(ps_p, 32);
  float* sred = (float*)(smem + 65536);  // 4 waves x 32 x 2 f32 = 1 KB
  if (l < 32) {
    sred[(w * 32 + l31) * 2] = s_p;
    sred[(w * 32 + l31) * 2 + 1] = ps_p;
  }
  __syncthreads();
  if (vh == 0 && l < 32) {
    float stot = s_p + sred[(((w ^ 1) * 32) + l31) * 2];
    float ptot = ps_p + sred[(((w ^ 1) * 32) + l31) * 2 + 1];
    sgp[(size_t)js * NROWS + qrow] = stot;
    psp[(size_t)js * NROWS + qrow] = ptot;
  }
  // stage acc (bf16) into padded LDS tile [64][264]
  __bf16* st = (__bf16*)smem;
#pragma unroll
  for (int tt = 0; tt < 4; ++tt)
#pragma unroll
    for (int r = 0; r < 16; ++r) {
      int row = qh * 32 + (r & 3) + 8 * (r >> 2) + 4 * g;
      int col = vh * 128 + tt * 32 + l31;
      st[row * 264 + col] = (__bf16)acc[tt][r];
    }
  __syncthreads();
  // linear copy LDS -> accp: 16B/lane, consecutive lanes -> consecutive 16B
  __bf16* dst = accp + ((size_t)js * NROWS + qb * 64) * DM;
#pragma unroll
  for (int p = 0; p < 8; ++p) {
    int off16 = p * 256 + t;   // 16B-granule index, 0..2047 (32 KB payload)
    int row = off16 >> 5;      // 32 granules (512 B) per row
    int colg = off16 & 31;
    bf16x8 v = *(const bf16x8*)&st[row * 264 + colg * 8];
    *(bf16x8*)&dst[(size_t)row * DM + colg * 8] = v;
  }
}

// ---- combine: sum 4 js partials; out=acc/s; res=x1+out; normalize; loss ----
__global__ __launch_bounds__(1024) void combine_kernel(
    const __bf16* __restrict__ accp, const float* __restrict__ sgp,
    const float* __restrict__ psp, const int* __restrict__ counts,
    const int* __restrict__ lab1, const float* __restrict__ x1,
    __bf16* __restrict__ resn, float* __restrict__ loss_out) {
  __shared__ float lred[16];
  const int t = threadIdx.x;
  const int rr = t >> 6;
  const int r = blockIdx.x * 16 + rr;
  const int l = t & 63;
  float s = 0.f;
#pragma unroll
  for (int js = 0; js < JSPLIT; ++js) s += sgp[(size_t)js * NROWS + r];
  const float inv = 1.f / s;
  float a0 = 0.f, a1 = 0.f, a2 = 0.f, a3 = 0.f;
#pragma unroll
  for (int js = 0; js < JSPLIT; ++js) {
    bf16x4 v = *(const bf16x4*)&accp[((size_t)js * NROWS + r) * DM + l * 4];
    a0 += (float)v[0]; a1 += (float)v[1]; a2 += (float)v[2]; a3 += (float)v[3];
  }
  float4 x = *(const float4*)&x1[(size_t)r * DM + l * 4];
  float o0 = x.x + a0 * inv, o1 = x.y + a1 * inv;
  float o2 = x.z + a2 * inv, o3 = x.w + a3 * inv;
  float sq = o0 * o0 + o1 * o1 + o2 * o2 + o3 * o3;
#pragma unroll
  for (int m = 1; m < 64; m <<= 1) sq += __shfl_xor(sq, m);
  const float nrm = 1.f / fmaxf(sqrtf(sq), 1e-12f);
  bf16x4 o;
  o[0] = (__bf16)(o0 * nrm); o[1] = (__bf16)(o1 * nrm);
  o[2] = (__bf16)(o2 * nrm); o[3] = (__bf16)(o3 * nrm);
  *(bf16x4*)&resn[(size_t)r * DM + l * 4] = o;
  if (l == 0) {
    float ps = 0.f;
#pragma unroll
    for (int js = 0; js < JSPLIT; ++js) ps += psp[(size_t)js * NROWS + r];
    float np = (float)counts[lab1[r] & 15];
    lred[rr] = (ps * LN2F - np * logf(s)) / fmaxf(np, 1.f);
  }
  __syncthreads();
  if (t == 0) {
    float accl = 0.f;
#pragma unroll
    for (int i = 0; i < 16; ++i) accl += lred[i];
    atomicAdd(loss_out, -accl * (1.f / 8192.f));
  }
}

// ---- final GEMM: out[m][n] = relu(resn@Wout + bout), scalar f32 stores ----
__global__ __launch_bounds__(256) void final_gemm(
    const __bf16* __restrict__ A, const __bf16* __restrict__ wmat,
    const float* __restrict__ bias, float* __restrict__ C) {
  __shared__ __bf16 W_s[64 * 256];
  const int t = threadIdx.x;
  const int w = t >> 6, l = t & 63, g = l >> 5, l31 = l & 31;
  const int mb = blockIdx.x, nt = blockIdx.y;
  const int n0 = nt * 64;
#pragma unroll
  for (int o = 0; o < 8; ++o) {
    int cbase = w * 64 + o * 256;
    int chunk = cbase + l;
    int n = chunk >> 5, kb = (chunk & 31) * 16;
    load_lds16((const char*)wmat + (size_t)(n0 + n) * 512 + (kb ^ ((n & 7) << 4)),
               (char*)W_s + (size_t)cbase * 16);
  }
  const int arow = mb * 128 + w * 32 + l31;
  bf16x8 af[16];
#pragma unroll
  for (int ks = 0; ks < 16; ++ks)
    af[ks] = *(const bf16x8*)&A[(size_t)arow * DM + ks * 16 + g * 8];
  __syncthreads();
  f32x16 acc2[2];
  acc2[0] = fzero16(); acc2[1] = fzero16();
#pragma unroll
  for (int ks = 0; ks < 16; ++ks)
#pragma unroll
    for (int tt = 0; tt < 2; ++tt) {
      int n = tt * 32 + l31;
      bf16x8 b = *(const bf16x8*)&W_s[n * DM + ((ks * 16 + g * 8) ^ ((n & 7) << 3))];
      acc2[tt] = __builtin_amdgcn_mfma_f32_32x32x16_bf16(af[ks], b, acc2[tt], 0, 0, 0);
    }
  const int mrowbase = mb * 128 + w * 32;
#pragma unroll
  for (int tt = 0; tt < 2; ++tt) {
    const int col = n0 + tt * 32 + l31;
    const float bv = bias[col];
#pragma unroll
    for (int rq = 0; rq < 4; ++rq)
#pragma unroll
      for (int j = 0; j < 4; ++j) {
        int m = mrowbase + j + 8 * rq + 4 * g;
        C[(size_t)m * DM + col] = fmaxf(acc2[tt][rq * 4 + j] + bv, 0.f);
      }
  }
}

extern "C" void kernel_launch(void* const* d_in, const int* in_sizes, int n_in,
                              void* d_out, int out_size, void* d_ws, size_t ws_size,
                              hipStream_t stream) {
  const float* x1 = (const float*)d_in[0];
  const float* x2 = (const float*)d_in[1];
  const int* lab1 = (const int*)d_in[2];
  const int* lab2 = (const int*)d_in[3];
  const float* Wxq = (const float*)d_in[4];
  const float* bxq = (const float*)d_in[5];
  const float* Wxk = (const float*)d_in[6];
  const float* bxk = (const float*)d_in[7];
  const float* Wxv = (const float*)d_in[8];
  const float* bxv = (const float*)d_in[9];
  const float* Wout = (const float*)d_in[10];
  const float* bout = (const float*)d_in[11];
  float* out = (float*)d_out;

  char* ws = (char*)d_ws;
  __bf16* xqb = (__bf16*)ws;                                // 4 MB
  __bf16* xkb = (__bf16*)(ws + (4 << 20));                  // 4 MB
  __bf16* xvT = (__bf16*)(ws + (8 << 20));                  // 4 MB [256][8192]
  __bf16* wt  = (__bf16*)(ws + (12 << 20));                 // 512 KB
  int* counts = (int*)(ws + (12 << 20) + (512 << 10));      // 64 B
  __bf16* accp = (__bf16*)(ws + (13 << 20));                // 16 MB [4][8192][256]
  float* sgp  = (float*)(ws + (29 << 20));                  // 128 KB [4][8192]
  float* psp  = (float*)(ws + (29 << 20) + (128 << 10));    // 128 KB
  __bf16* resn = xqb;  // alias: xqb dead after flash

  prep_kernel<<<dim3(65), dim3(256), 0, stream>>>(Wxq, Wxk, Wxv, Wout, wt,
                                                  lab2, counts, out);

  proj3_kernel<<<dim3(64, 1, 3), dim3(256), 0, stream>>>(
      x1, x2, wt, bxq, bxk, bxv, xqb, xkb, xvT);

  flash_kernel<<<dim3(512), dim3(256), 0, stream>>>(
      xqb, xkb, xvT, lab1, lab2, accp, sgp, psp);

  combine_kernel<<<dim3(512), dim3(1024), 0, stream>>>(
      accp, sgp, psp, counts, lab1, x1, resn, out);

  final_gemm<<<dim3(64, 4), dim3(256), 0, stream>>>(resn, wt + 196608, bout,
                                                    out + 1);
}